// Round 17
// baseline (573.899 us; speedup 1.0000x reference)
//
#include <hip/hip_runtime.h>

// OnceAggregation R17: recombination of proven-best halves.
//   point_fused = R13 exact (plain gemm2x, no setprio, no prefetch; 235us proven).
//   scatter_prep2 = R16 (unroll 16; tail improvement proven).
//   Everything else identical to R13/R16 (both passed).
//   memset ; pack_hist ; scan ; scatter_prep2 ; point_fused ; vox_fused.

typedef __attribute__((ext_vector_type(4))) float f32x4;
typedef __attribute__((ext_vector_type(8))) short s16x8;
typedef __attribute__((ext_vector_type(2))) unsigned int u32x2;
typedef __attribute__((ext_vector_type(4))) unsigned int u32x4;

static constexpr int NP = 500000;   // 32 | NP ; 500000 = 7812*64 + 32
static constexpr int NV = 60000;

__device__ __forceinline__ unsigned short f2bf(float f){
  unsigned int u = __float_as_uint(f);
  u = (u + 0x7FFFu + ((u >> 16) & 1u)) >> 16;   // RNE
  return (unsigned short)u;
}

__device__ __forceinline__ unsigned int cvtpk(float lo, float hi){
  unsigned int r;
  asm("v_cvt_pk_bf16_f32 %0, %1, %2" : "=v"(r) : "v"(lo), "v"(hi));
  return r;
}

__device__ __forceinline__ unsigned int pkmaxu16(unsigned int a, unsigned int b){
  unsigned int r;
  asm("v_pk_max_u16 %0, %1, %2" : "=v"(r) : "v"(a), "v"(b));
  return r;
}

// ---------------- pack weights + out_coors + histogram ----------------
__device__ __forceinline__ void pack_one(const float* __restrict__ w,
                                         unsigned short* __restrict__ dst,
                                         int K, int C, bool perm, int idx){
  int j = idx & 7, l = (idx >> 3) & 63, rest = idx >> 9;
  int kcn = K >> 5;
  int kc = rest % kcn, n = rest / kcn;
  int g = l >> 4, t = l & 15;
  int k = perm ? (kc * 32 + ((j >> 2) << 4) + g * 4 + (j & 3))
               : (kc * 32 + g * 8 + j);
  dst[idx] = f2bf(w[(size_t)k * C + n * 16 + t]);
}

__global__ void pack_hist_kernel(const float* __restrict__ w1, const float* __restrict__ w2,
                                 const float* __restrict__ ow, const float* __restrict__ pw1,
                                 const float* __restrict__ pw2,
                                 unsigned short* __restrict__ w1p, unsigned short* __restrict__ w2p,
                                 unsigned short* __restrict__ owp, unsigned short* __restrict__ pw1p,
                                 unsigned short* __restrict__ pw2p,
                                 float* __restrict__ out_coors,
                                 const int* __restrict__ coors, int* __restrict__ counts){
  int stride = gridDim.x * blockDim.x;
  const int T = 196608 + NV + NP;
  for (int i = blockIdx.x * blockDim.x + threadIdx.x; i < T; i += stride){
    if      (i < 16384)       pack_one(w1,  w1p,  128, 128, false, i);
    else if (i < 49152)       pack_one(w2,  w2p,  128, 256, true,  i - 16384);
    else if (i < 65536)       pack_one(ow,  owp,  256, 64,  true,  i - 49152);
    else if (i < 131072)      pack_one(pw1, pw1p, 256, 256, true,  i - 65536);
    else if (i < 196608)      pack_one(pw2, pw2p, 256, 256, true,  i - 131072);
    else if (i < 196608 + NV) out_coors[i - 196608] = (float)(i - 196608);
    else                      atomicAdd(&counts[coors[i - 196608 - NV]], 1);
  }
}

// ---------------- counting sort: coalesced scan ----------------
__global__ __launch_bounds__(1024)
void scan_kernel(const int* __restrict__ counts, int* __restrict__ cursor){
  __shared__ int part[1024];
  const int t = threadIdx.x;
  constexpr int PER = (NV + 1023) / 1024;   // 59
  int s = 0;
#pragma unroll
  for (int i = 0; i < PER; ++i){ int v = i * 1024 + t; if (v < NV) s += counts[v]; }
  part[t] = s;
  __syncthreads();
  for (int d = 1; d < 1024; d <<= 1){
    int u = (t >= d) ? part[t - d] : 0;
    __syncthreads();
    part[t] += u;
    __syncthreads();
  }
  int run = (t > 0) ? part[t - 1] : 0;
#pragma unroll
  for (int i = 0; i < PER; ++i){
    int v = i * 1024 + t;
    if (v < NV){ cursor[v] = run; run += counts[v]; }
  }
}

// ---------------- wave-cooperative scatter + full-line bf16 row permute ----------------
__global__ void scatter_prep2_kernel(const int* __restrict__ coors, int* __restrict__ cursor,
                                     const float* __restrict__ feats,
                                     const float* __restrict__ fclus,
                                     int2* __restrict__ pv,
                                     unsigned int* __restrict__ x0u){
  const int lane = threadIdx.x & 63;
  const int wid  = (blockIdx.x * blockDim.x + threadIdx.x) >> 6;
  const int nw   = (gridDim.x * blockDim.x) >> 6;
  const int NB = NP >> 6;              // 7812 full batches
  const int c0 = 2 * lane, c1 = c0 + 1;
  const float s0 = (c0 >= 125) ? ((c0 == 127) ? 0.25f : 0.05f) : 1.f;
  const float s1 = (c1 >= 125) ? ((c1 == 127) ? 0.25f : 0.05f) : 1.f;

  for (int b = wid; b <= NB; b += nw){
    if (b < NB){
      const int i = b * 64 + lane;
      int v = coors[i];
      int p = atomicAdd(&cursor[v], 1);
      pv[p] = make_int2(i, v);
#pragma unroll 16
      for (int j = 0; j < 64; ++j){
        const int ij = b * 64 + j;
        const int pj = __shfl(p, j);
        const float* rp = feats + (size_t)ij * 125;
        const float* fc = fclus + (size_t)ij * 3;
        float v0 = (c0 < 125) ? rp[c0] : fc[c0 - 125];
        float v1 = (c1 < 125) ? rp[c1] : fc[c1 - 125];
        x0u[(size_t)pj * 64 + lane] = cvtpk(v0 * s0, v1 * s1);
      }
    } else {
      const int i = b * 64 + lane;
      int p = 0;
      if (lane < 32){
        int v = coors[i];
        p = atomicAdd(&cursor[v], 1);
        pv[p] = make_int2(i, v);
      }
#pragma unroll 16
      for (int j = 0; j < 32; ++j){
        const int ij = b * 64 + j;
        const int pj = __shfl(p, j);
        const float* rp = feats + (size_t)ij * 125;
        const float* fc = fclus + (size_t)ij * 3;
        float v0 = (c0 < 125) ? rp[c0] : fc[c0 - 125];
        float v1 = (c1 < 125) ? rp[c1] : fc[c1 - 125];
        x0u[(size_t)pj * 64 + lane] = cvtpk(v0 * s0, v1 * s1);
      }
    }
  }
}

// ---------------- swapped-GEMM building blocks (R13 plain form) ----------------
template<int KC, int NT>
__device__ __forceinline__ void gemm2x(const s16x8* bA, const s16x8* bB,
                                       const unsigned short* __restrict__ Wp,
                                       int lane, f32x4* dA, f32x4* dB){
#pragma unroll
  for (int n = 0; n < NT; ++n){
    f32x4 aA = {0.f,0.f,0.f,0.f}, aB = {0.f,0.f,0.f,0.f};
#pragma unroll
    for (int kc = 0; kc < KC; ++kc){
      s16x8 w = *(const s16x8*)(Wp + ((n * KC + kc) * 64 + lane) * 8);
      aA = __builtin_amdgcn_mfma_f32_16x16x32_bf16(w, bA[kc], aA, 0, 0, 0);
      aB = __builtin_amdgcn_mfma_f32_16x16x32_bf16(w, bB[kc], aB, 0, 0, 0);
    }
    dA[n] = aA; dB[n] = aB;
  }
}

template<int NT, int C>
__device__ __forceinline__ void bias_ln_relu_sw(f32x4* d0, f32x4* d1,
                                                const float* __restrict__ bias,
                                                const float* __restrict__ gam,
                                                const float* __restrict__ bet, int g){
  float s0 = 0.f, s1 = 0.f, q0 = 0.f, q1 = 0.f;
#pragma unroll
  for (int n = 0; n < NT; ++n){
    f32x4 bv = *(const f32x4*)(bias + n * 16 + g * 4);
#pragma unroll
    for (int i = 0; i < 4; ++i){
      float v0 = d0[n][i] + bv[i]; d0[n][i] = v0; s0 += v0; q0 += v0 * v0;
      float v1 = d1[n][i] + bv[i]; d1[n][i] = v1; s1 += v1; q1 += v1 * v1;
    }
  }
  s0 += __shfl_xor(s0, 16); s0 += __shfl_xor(s0, 32);
  q0 += __shfl_xor(q0, 16); q0 += __shfl_xor(q0, 32);
  s1 += __shfl_xor(s1, 16); s1 += __shfl_xor(s1, 32);
  q1 += __shfl_xor(q1, 16); q1 += __shfl_xor(q1, 32);
  float m0 = s0 * (1.f / C), m1 = s1 * (1.f / C);
  float r0 = rsqrtf(q0 * (1.f / C) - m0 * m0 + 1e-3f);
  float r1 = rsqrtf(q1 * (1.f / C) - m1 * m1 + 1e-3f);
#pragma unroll
  for (int n = 0; n < NT; ++n){
    f32x4 gv  = *(const f32x4*)(gam + n * 16 + g * 4);
    f32x4 bev = *(const f32x4*)(bet + n * 16 + g * 4);
#pragma unroll
    for (int i = 0; i < 4; ++i){
      d0[n][i] = fmaxf((d0[n][i] - m0) * r0 * gv[i] + bev[i], 0.f);
      d1[n][i] = fmaxf((d1[n][i] - m1) * r1 * gv[i] + bev[i], 0.f);
    }
  }
}

template<int NT>
__device__ __forceinline__ void to_frags(const f32x4* d, s16x8* f){
#pragma unroll
  for (int kc = 0; kc < NT / 2; ++kc){
    u32x4 t;
    t[0] = cvtpk(d[2*kc][0],   d[2*kc][1]);
    t[1] = cvtpk(d[2*kc][2],   d[2*kc][3]);
    t[2] = cvtpk(d[2*kc+1][0], d[2*kc+1][1]);
    t[3] = cvtpk(d[2*kc+1][2], d[2*kc+1][3]);
    f[kc] = __builtin_bit_cast(s16x8, t);
  }
}

// flush lane's 4 channels of run max (2 packed u32) for voxel v.
__device__ __forceinline__ void flush4(float* __restrict__ agg, int v, int lane,
                                       unsigned int q0, unsigned int q1, bool partial){
  float* base = agg + (size_t)v * 256 + lane * 4;
  unsigned int a0 = q0 << 16, a1 = q0 & 0xffff0000u;
  unsigned int a2 = q1 << 16, a3 = q1 & 0xffff0000u;
  if (!partial){
    f32x4 o;
    o[0] = __uint_as_float(a0); o[1] = __uint_as_float(a1);
    o[2] = __uint_as_float(a2); o[3] = __uint_as_float(a3);
    *(f32x4*)base = o;
  } else {
    unsigned int* ab = (unsigned int*)base;
    atomicMax(ab + 0, a0); atomicMax(ab + 1, a1);
    atomicMax(ab + 2, a2); atomicMax(ab + 3, a3);
  }
}

// ---------------- fused point pipeline (R13 exact) ----------------
__global__ __launch_bounds__(256, 2)
void point_fused_kernel(const unsigned short* __restrict__ x0,
                        const int2* __restrict__ pv,
                        const unsigned short* __restrict__ w1p,
                        const unsigned short* __restrict__ w2p,
                        const unsigned short* __restrict__ owp,
                        const float* __restrict__ b1, const float* __restrict__ g1,
                        const float* __restrict__ be1,
                        const float* __restrict__ b2, const float* __restrict__ g2,
                        const float* __restrict__ be2,
                        const float* __restrict__ ob, const float* __restrict__ og,
                        const float* __restrict__ obe,
                        float* __restrict__ agg,
                        float* __restrict__ out_pts){
  __shared__ __align__(16) unsigned short tile[4][32 * 256];   // 16 KB per wave
  const int lane = threadIdx.x & 63;
  const int wave = threadIdx.x >> 6;
  const int g = lane >> 4, t = lane & 15;
  const int m0 = blockIdx.x * 128 + wave * 32;   // 32 | NP
  if (m0 >= NP) return;                          // per-wave LDS: no barrier needed
  const int slotA = m0 + t, slotB = m0 + 16 + t;
  const int2 pA = pv[slotA];
  const int2 pB = pv[slotB];
  const int origA = pA.x, origB = pB.x;
  const int myv = pv[m0 + (lane & 31)].y;        // wave's 32 voxel ids

  // sequential fragment loads from sorted x0
  s16x8 bfA[4], bfB[4];
#pragma unroll
  for (int kc = 0; kc < 4; ++kc){
    bfA[kc] = *(const s16x8*)(x0 + (size_t)slotA * 128 + (kc * 4 + g) * 8);
    bfB[kc] = *(const s16x8*)(x0 + (size_t)slotB * 128 + (kc * 4 + g) * 8);
  }

  f32x4 d1a[8], d1b[8];
  gemm2x<4, 8>(bfA, bfB, w1p, lane, d1a, d1b);
  bias_ln_relu_sw<8, 128>(d1a, d1b, b1, g1, be1, g);
  s16x8 f2a[4], f2b[4];
  to_frags<8>(d1a, f2a); to_frags<8>(d1b, f2b);

  f32x4 d2a[16], d2b[16];
  gemm2x<4, 16>(f2a, f2b, w2p, lane, d2a, d2b);
  bias_ln_relu_sw<16, 256>(d2a, d2b, b2, g2, be2, g);
  s16x8 f3a[8], f3b[8];
  to_frags<16>(d2a, f3a); to_frags<16>(d2b, f3b);

  // stage y2 tile to this wave's LDS quarter (swizzled 16B slots)
  unsigned short* my = tile[wave];
  const int rA = t, rB = t + 16;
#pragma unroll
  for (int kc = 0; kc < 8; ++kc){
    int s = kc * 4 + g;
    int spA = (s & ~7) | ((s & 7) ^ (rA & 7));
    int spB = (s & ~7) | ((s & 7) ^ (rB & 7));
    *(s16x8*)&my[rA * 256 + spA * 8] = f3a[kc];
    *(s16x8*)&my[rB * 256 + spB * 8] = f3b[kc];
  }

  // out layer (overlaps LDS write drain) -> scatter to original point order
  {
    f32x4 d3a[4], d3b[4];
    gemm2x<8, 4>(f3a, f3b, owp, lane, d3a, d3b);
    bias_ln_relu_sw<4, 64>(d3a, d3b, ob, og, obe, g);
#pragma unroll
    for (int n = 0; n < 4; ++n){
      *(f32x4*)(out_pts + (size_t)origA * 64 + n * 16 + g * 4) = d3a[n];
      *(f32x4*)(out_pts + (size_t)origB * 64 + n * 16 + g * 4) = d3b[n];
    }
  }

  // ---- chunked wave-uniform run walk (4 chunks x 8 rows; 8 ds_reads in flight) ----
  const int vleft  = (m0 > 0) ? pv[m0 - 1].y : -1;
  const int vright = (m0 + 32 < NP) ? pv[m0 + 32].y : -1;
  const int slot = lane >> 1;                 // 16B slot holding lane's channels
  const int half = (lane & 1) * 4;            // u16 offset within slot
  unsigned int q0 = 0, q1 = 0;
  int cur = __shfl(myv, 0);
  int rs = 0;
#pragma unroll
  for (int rc = 0; rc < 4; ++rc){
    u32x2 dreg[8];
#pragma unroll
    for (int rr = 0; rr < 8; ++rr){
      int r = rc * 8 + rr;
      int sp = (slot & ~7) | ((slot & 7) ^ (r & 7));
      dreg[rr] = *(const u32x2*)&my[r * 256 + sp * 8 + half];
    }
#pragma unroll
    for (int rr = 0; rr < 8; ++rr){
      int r = rc * 8 + rr;
      int v = __shfl(myv, r);                 // uniform broadcast (readlane)
      if (v != cur){
        flush4(agg, cur, lane, q0, q1, rs == 0 && cur == vleft);
        q0 = 0; q1 = 0; cur = v; rs = r;
      }
      q0 = pkmaxu16(q0, dreg[rr][0]);
      q1 = pkmaxu16(q1, dreg[rr][1]);
    }
  }
  flush4(agg, cur, lane, q0, q1, (rs == 0 && cur == vleft) || cur == vright);
}

// ---------------- fused voxel pipeline (agg f32 -> pl1 -> pl2) ----------------
__global__ __launch_bounds__(256, 2)
void vox_fused_kernel(const float* __restrict__ agg,
                      const unsigned short* __restrict__ pw1p,
                      const unsigned short* __restrict__ pw2p,
                      const float* __restrict__ pb1, const float* __restrict__ pg1,
                      const float* __restrict__ pbe1,
                      const float* __restrict__ pb2, const float* __restrict__ pg2,
                      const float* __restrict__ pbe2,
                      float* __restrict__ out_vox){
  const int lane = threadIdx.x & 63;
  const int wave = threadIdx.x >> 6;
  const int m0 = blockIdx.x * 128 + wave * 32;
  if (m0 >= NV) return;
  const int g = lane >> 4, t = lane & 15;
  const size_t mA = m0 + t, mB = m0 + 16 + t;

  s16x8 bfA[8], bfB[8];
#pragma unroll
  for (int kc = 0; kc < 8; ++kc){
    const float* pa = agg + mA * 256 + kc * 32 + g * 8;
    const float* pb = agg + mB * 256 + kc * 32 + g * 8;
    f32x4 a0 = *(const f32x4*)pa, a1 = *(const f32x4*)(pa + 4);
    f32x4 b0 = *(const f32x4*)pb, b1v = *(const f32x4*)(pb + 4);
    u32x4 ta, tb;
    ta[0] = cvtpk(a0[0], a0[1]); ta[1] = cvtpk(a0[2], a0[3]);
    ta[2] = cvtpk(a1[0], a1[1]); ta[3] = cvtpk(a1[2], a1[3]);
    tb[0] = cvtpk(b0[0], b0[1]); tb[1] = cvtpk(b0[2], b0[3]);
    tb[2] = cvtpk(b1v[0], b1v[1]); tb[3] = cvtpk(b1v[2], b1v[3]);
    bfA[kc] = __builtin_bit_cast(s16x8, ta);
    bfB[kc] = __builtin_bit_cast(s16x8, tb);
  }
  f32x4 da[16], db[16];
  gemm2x<8, 16>(bfA, bfB, pw1p, lane, da, db);
  bias_ln_relu_sw<16, 256>(da, db, pb1, pg1, pbe1, g);

  s16x8 fa[8], fb[8];
  to_frags<16>(da, fa); to_frags<16>(db, fb);

  gemm2x<8, 16>(fa, fb, pw2p, lane, da, db);
  bias_ln_relu_sw<16, 256>(da, db, pb2, pg2, pbe2, g);
#pragma unroll
  for (int n = 0; n < 16; ++n){
    *(f32x4*)(out_vox + mA * 256 + n * 16 + g * 4) = da[n];
    *(f32x4*)(out_vox + mB * 256 + n * 16 + g * 4) = db[n];
  }
}

extern "C" void kernel_launch(void* const* d_in, const int* in_sizes, int n_in,
                              void* d_out, int out_size, void* d_ws, size_t ws_size,
                              hipStream_t stream){
  const float* features  = (const float*)d_in[1];
  const int*   coors     = (const int*)  d_in[2];
  const float* f_cluster = (const float*)d_in[3];
  const float* w1  = (const float*)d_in[4];
  const float* b1  = (const float*)d_in[5];
  const float* g1  = (const float*)d_in[6];
  const float* be1 = (const float*)d_in[7];
  const float* w2  = (const float*)d_in[8];
  const float* b2  = (const float*)d_in[9];
  const float* g2  = (const float*)d_in[10];
  const float* be2 = (const float*)d_in[11];
  const float* pw1 = (const float*)d_in[12];
  const float* pb1 = (const float*)d_in[13];
  const float* pg1 = (const float*)d_in[14];
  const float* pbe1= (const float*)d_in[15];
  const float* pw2 = (const float*)d_in[16];
  const float* pb2 = (const float*)d_in[17];
  const float* pg2 = (const float*)d_in[18];
  const float* pbe2= (const float*)d_in[19];
  const float* ow  = (const float*)d_in[20];
  const float* ob  = (const float*)d_in[21];
  const float* og  = (const float*)d_in[22];
  const float* obe = (const float*)d_in[23];

  char* ws = (char*)d_ws;
  float* aggf   = (float*)(ws + 0);                          // 61,440,000 B
  int* counts   = (int*)(ws + 61440000ull);                  // memset with aggf
  int* cursor   = (int*)(ws + 61800000ull);
  int2* pv      = (int2*)(ws + 62100000ull);                 // 4,000,000 B
  unsigned int* x0u = (unsigned int*)(ws + 66200000ull);     // 128,000,000 B (sorted order)
  unsigned short* x0 = (unsigned short*)x0u;
  unsigned short* w1p = (unsigned short*)(ws + 195000000ull);
  unsigned short* w2p = (unsigned short*)(ws + 195000000ull + 1*262144ull);
  unsigned short* owp = (unsigned short*)(ws + 195000000ull + 2*262144ull);
  unsigned short* pw1p= (unsigned short*)(ws + 195000000ull + 3*262144ull);
  unsigned short* pw2p= (unsigned short*)(ws + 195000000ull + 4*262144ull);

  float* outp      = (float*)d_out;
  float* out_pts   = outp;                       // [N,64]
  float* out_vox   = outp + 32000000;            // [V,256]
  float* out_coors = outp + 47360000;            // [V] as float

  hipMemsetAsync(ws, 0, 61440000ull + (size_t)NV * sizeof(int), stream);

  pack_hist_kernel<<<2048, 256, 0, stream>>>(w1, w2, ow, pw1, pw2,
                                             w1p, w2p, owp, pw1p, pw2p,
                                             out_coors, coors, counts);

  scan_kernel<<<1, 1024, 0, stream>>>(counts, cursor);

  scatter_prep2_kernel<<<2048, 256, 0, stream>>>(coors, cursor, features, f_cluster,
                                                 pv, x0u);

  point_fused_kernel<<<(NP + 127) / 128, 256, 0, stream>>>(
      x0, pv, w1p, w2p, owp,
      b1, g1, be1, b2, g2, be2, ob, og, obe, aggf, out_pts);

  vox_fused_kernel<<<(NV + 127) / 128, 256, 0, stream>>>(
      aggf, pw1p, pw2p, pb1, pg1, pbe1, pb2, pg2, pbe2, out_vox);
}

// Round 18
// 500.764 us; speedup vs baseline: 1.1460x; 1.1460x over previous
//
#include <hip/hip_runtime.h>

// OnceAggregation R18: per-kernel-best recombination.
//   point_fused: R13-plain gemm2x (235-236us, proven x3).
//   vox_fused:   R16-pipelined gemm2x_pl (weight prefetch; the only mechanistic
//                candidate for R16's better tail).
//   scatter_prep2: unroll 16. Rest identical to R17 (passed).
//   memset ; pack_hist ; scan ; scatter_prep2 ; point_fused ; vox_fused.

typedef __attribute__((ext_vector_type(4))) float f32x4;
typedef __attribute__((ext_vector_type(8))) short s16x8;
typedef __attribute__((ext_vector_type(2))) unsigned int u32x2;
typedef __attribute__((ext_vector_type(4))) unsigned int u32x4;

static constexpr int NP = 500000;   // 32 | NP ; 500000 = 7812*64 + 32
static constexpr int NV = 60000;

__device__ __forceinline__ unsigned short f2bf(float f){
  unsigned int u = __float_as_uint(f);
  u = (u + 0x7FFFu + ((u >> 16) & 1u)) >> 16;   // RNE
  return (unsigned short)u;
}

__device__ __forceinline__ unsigned int cvtpk(float lo, float hi){
  unsigned int r;
  asm("v_cvt_pk_bf16_f32 %0, %1, %2" : "=v"(r) : "v"(lo), "v"(hi));
  return r;
}

__device__ __forceinline__ unsigned int pkmaxu16(unsigned int a, unsigned int b){
  unsigned int r;
  asm("v_pk_max_u16 %0, %1, %2" : "=v"(r) : "v"(a), "v"(b));
  return r;
}

// ---------------- pack weights + out_coors + histogram ----------------
__device__ __forceinline__ void pack_one(const float* __restrict__ w,
                                         unsigned short* __restrict__ dst,
                                         int K, int C, bool perm, int idx){
  int j = idx & 7, l = (idx >> 3) & 63, rest = idx >> 9;
  int kcn = K >> 5;
  int kc = rest % kcn, n = rest / kcn;
  int g = l >> 4, t = l & 15;
  int k = perm ? (kc * 32 + ((j >> 2) << 4) + g * 4 + (j & 3))
               : (kc * 32 + g * 8 + j);
  dst[idx] = f2bf(w[(size_t)k * C + n * 16 + t]);
}

__global__ void pack_hist_kernel(const float* __restrict__ w1, const float* __restrict__ w2,
                                 const float* __restrict__ ow, const float* __restrict__ pw1,
                                 const float* __restrict__ pw2,
                                 unsigned short* __restrict__ w1p, unsigned short* __restrict__ w2p,
                                 unsigned short* __restrict__ owp, unsigned short* __restrict__ pw1p,
                                 unsigned short* __restrict__ pw2p,
                                 float* __restrict__ out_coors,
                                 const int* __restrict__ coors, int* __restrict__ counts){
  int stride = gridDim.x * blockDim.x;
  const int T = 196608 + NV + NP;
  for (int i = blockIdx.x * blockDim.x + threadIdx.x; i < T; i += stride){
    if      (i < 16384)       pack_one(w1,  w1p,  128, 128, false, i);
    else if (i < 49152)       pack_one(w2,  w2p,  128, 256, true,  i - 16384);
    else if (i < 65536)       pack_one(ow,  owp,  256, 64,  true,  i - 49152);
    else if (i < 131072)      pack_one(pw1, pw1p, 256, 256, true,  i - 65536);
    else if (i < 196608)      pack_one(pw2, pw2p, 256, 256, true,  i - 131072);
    else if (i < 196608 + NV) out_coors[i - 196608] = (float)(i - 196608);
    else                      atomicAdd(&counts[coors[i - 196608 - NV]], 1);
  }
}

// ---------------- counting sort: coalesced scan ----------------
__global__ __launch_bounds__(1024)
void scan_kernel(const int* __restrict__ counts, int* __restrict__ cursor){
  __shared__ int part[1024];
  const int t = threadIdx.x;
  constexpr int PER = (NV + 1023) / 1024;   // 59
  int s = 0;
#pragma unroll
  for (int i = 0; i < PER; ++i){ int v = i * 1024 + t; if (v < NV) s += counts[v]; }
  part[t] = s;
  __syncthreads();
  for (int d = 1; d < 1024; d <<= 1){
    int u = (t >= d) ? part[t - d] : 0;
    __syncthreads();
    part[t] += u;
    __syncthreads();
  }
  int run = (t > 0) ? part[t - 1] : 0;
#pragma unroll
  for (int i = 0; i < PER; ++i){
    int v = i * 1024 + t;
    if (v < NV){ cursor[v] = run; run += counts[v]; }
  }
}

// ---------------- wave-cooperative scatter + full-line bf16 row permute ----------------
__global__ void scatter_prep2_kernel(const int* __restrict__ coors, int* __restrict__ cursor,
                                     const float* __restrict__ feats,
                                     const float* __restrict__ fclus,
                                     int2* __restrict__ pv,
                                     unsigned int* __restrict__ x0u){
  const int lane = threadIdx.x & 63;
  const int wid  = (blockIdx.x * blockDim.x + threadIdx.x) >> 6;
  const int nw   = (gridDim.x * blockDim.x) >> 6;
  const int NB = NP >> 6;              // 7812 full batches
  const int c0 = 2 * lane, c1 = c0 + 1;
  const float s0 = (c0 >= 125) ? ((c0 == 127) ? 0.25f : 0.05f) : 1.f;
  const float s1 = (c1 >= 125) ? ((c1 == 127) ? 0.25f : 0.05f) : 1.f;

  for (int b = wid; b <= NB; b += nw){
    if (b < NB){
      const int i = b * 64 + lane;
      int v = coors[i];
      int p = atomicAdd(&cursor[v], 1);
      pv[p] = make_int2(i, v);
#pragma unroll 16
      for (int j = 0; j < 64; ++j){
        const int ij = b * 64 + j;
        const int pj = __shfl(p, j);
        const float* rp = feats + (size_t)ij * 125;
        const float* fc = fclus + (size_t)ij * 3;
        float v0 = (c0 < 125) ? rp[c0] : fc[c0 - 125];
        float v1 = (c1 < 125) ? rp[c1] : fc[c1 - 125];
        x0u[(size_t)pj * 64 + lane] = cvtpk(v0 * s0, v1 * s1);
      }
    } else {
      const int i = b * 64 + lane;
      int p = 0;
      if (lane < 32){
        int v = coors[i];
        p = atomicAdd(&cursor[v], 1);
        pv[p] = make_int2(i, v);
      }
#pragma unroll 16
      for (int j = 0; j < 32; ++j){
        const int ij = b * 64 + j;
        const int pj = __shfl(p, j);
        const float* rp = feats + (size_t)ij * 125;
        const float* fc = fclus + (size_t)ij * 3;
        float v0 = (c0 < 125) ? rp[c0] : fc[c0 - 125];
        float v1 = (c1 < 125) ? rp[c1] : fc[c1 - 125];
        x0u[(size_t)pj * 64 + lane] = cvtpk(v0 * s0, v1 * s1);
      }
    }
  }
}

// ---------------- swapped-GEMM building blocks ----------------
// plain (point_fused; proven 235us)
template<int KC, int NT>
__device__ __forceinline__ void gemm2x(const s16x8* bA, const s16x8* bB,
                                       const unsigned short* __restrict__ Wp,
                                       int lane, f32x4* dA, f32x4* dB){
#pragma unroll
  for (int n = 0; n < NT; ++n){
    f32x4 aA = {0.f,0.f,0.f,0.f}, aB = {0.f,0.f,0.f,0.f};
#pragma unroll
    for (int kc = 0; kc < KC; ++kc){
      s16x8 w = *(const s16x8*)(Wp + ((n * KC + kc) * 64 + lane) * 8);
      aA = __builtin_amdgcn_mfma_f32_16x16x32_bf16(w, bA[kc], aA, 0, 0, 0);
      aB = __builtin_amdgcn_mfma_f32_16x16x32_bf16(w, bB[kc], aB, 0, 0, 0);
    }
    dA[n] = aA; dB[n] = aB;
  }
}

// pipelined (vox_fused; R16 form — prefetch n+1's weight fragments)
template<int KC, int NT>
__device__ __forceinline__ void gemm2x_pl(const s16x8* bA, const s16x8* bB,
                                          const unsigned short* __restrict__ Wp,
                                          int lane, f32x4* dA, f32x4* dB){
  s16x8 wc[KC], wn[KC];
#pragma unroll
  for (int kc = 0; kc < KC; ++kc)
    wc[kc] = *(const s16x8*)(Wp + ((size_t)kc * 64 + lane) * 8);
#pragma unroll
  for (int n = 0; n < NT; ++n){
    if (n + 1 < NT){
#pragma unroll
      for (int kc = 0; kc < KC; ++kc)
        wn[kc] = *(const s16x8*)(Wp + ((size_t)((n + 1) * KC + kc) * 64 + lane) * 8);
    }
    f32x4 aA = {0.f,0.f,0.f,0.f}, aB = {0.f,0.f,0.f,0.f};
#pragma unroll
    for (int kc = 0; kc < KC; ++kc){
      aA = __builtin_amdgcn_mfma_f32_16x16x32_bf16(wc[kc], bA[kc], aA, 0, 0, 0);
      aB = __builtin_amdgcn_mfma_f32_16x16x32_bf16(wc[kc], bB[kc], aB, 0, 0, 0);
    }
    dA[n] = aA; dB[n] = aB;
    if (n + 1 < NT){
#pragma unroll
      for (int kc = 0; kc < KC; ++kc) wc[kc] = wn[kc];
    }
  }
}

template<int NT, int C>
__device__ __forceinline__ void bias_ln_relu_sw(f32x4* d0, f32x4* d1,
                                                const float* __restrict__ bias,
                                                const float* __restrict__ gam,
                                                const float* __restrict__ bet, int g){
  float s0 = 0.f, s1 = 0.f, q0 = 0.f, q1 = 0.f;
#pragma unroll
  for (int n = 0; n < NT; ++n){
    f32x4 bv = *(const f32x4*)(bias + n * 16 + g * 4);
#pragma unroll
    for (int i = 0; i < 4; ++i){
      float v0 = d0[n][i] + bv[i]; d0[n][i] = v0; s0 += v0; q0 += v0 * v0;
      float v1 = d1[n][i] + bv[i]; d1[n][i] = v1; s1 += v1; q1 += v1 * v1;
    }
  }
  s0 += __shfl_xor(s0, 16); s0 += __shfl_xor(s0, 32);
  q0 += __shfl_xor(q0, 16); q0 += __shfl_xor(q0, 32);
  s1 += __shfl_xor(s1, 16); s1 += __shfl_xor(s1, 32);
  q1 += __shfl_xor(q1, 16); q1 += __shfl_xor(q1, 32);
  float m0 = s0 * (1.f / C), m1 = s1 * (1.f / C);
  float r0 = rsqrtf(q0 * (1.f / C) - m0 * m0 + 1e-3f);
  float r1 = rsqrtf(q1 * (1.f / C) - m1 * m1 + 1e-3f);
#pragma unroll
  for (int n = 0; n < NT; ++n){
    f32x4 gv  = *(const f32x4*)(gam + n * 16 + g * 4);
    f32x4 bev = *(const f32x4*)(bet + n * 16 + g * 4);
#pragma unroll
    for (int i = 0; i < 4; ++i){
      d0[n][i] = fmaxf((d0[n][i] - m0) * r0 * gv[i] + bev[i], 0.f);
      d1[n][i] = fmaxf((d1[n][i] - m1) * r1 * gv[i] + bev[i], 0.f);
    }
  }
}

template<int NT>
__device__ __forceinline__ void to_frags(const f32x4* d, s16x8* f){
#pragma unroll
  for (int kc = 0; kc < NT / 2; ++kc){
    u32x4 t;
    t[0] = cvtpk(d[2*kc][0],   d[2*kc][1]);
    t[1] = cvtpk(d[2*kc][2],   d[2*kc][3]);
    t[2] = cvtpk(d[2*kc+1][0], d[2*kc+1][1]);
    t[3] = cvtpk(d[2*kc+1][2], d[2*kc+1][3]);
    f[kc] = __builtin_bit_cast(s16x8, t);
  }
}

// flush lane's 4 channels of run max (2 packed u32) for voxel v.
__device__ __forceinline__ void flush4(float* __restrict__ agg, int v, int lane,
                                       unsigned int q0, unsigned int q1, bool partial){
  float* base = agg + (size_t)v * 256 + lane * 4;
  unsigned int a0 = q0 << 16, a1 = q0 & 0xffff0000u;
  unsigned int a2 = q1 << 16, a3 = q1 & 0xffff0000u;
  if (!partial){
    f32x4 o;
    o[0] = __uint_as_float(a0); o[1] = __uint_as_float(a1);
    o[2] = __uint_as_float(a2); o[3] = __uint_as_float(a3);
    *(f32x4*)base = o;
  } else {
    unsigned int* ab = (unsigned int*)base;
    atomicMax(ab + 0, a0); atomicMax(ab + 1, a1);
    atomicMax(ab + 2, a2); atomicMax(ab + 3, a3);
  }
}

// ---------------- fused point pipeline (R13 exact) ----------------
__global__ __launch_bounds__(256, 2)
void point_fused_kernel(const unsigned short* __restrict__ x0,
                        const int2* __restrict__ pv,
                        const unsigned short* __restrict__ w1p,
                        const unsigned short* __restrict__ w2p,
                        const unsigned short* __restrict__ owp,
                        const float* __restrict__ b1, const float* __restrict__ g1,
                        const float* __restrict__ be1,
                        const float* __restrict__ b2, const float* __restrict__ g2,
                        const float* __restrict__ be2,
                        const float* __restrict__ ob, const float* __restrict__ og,
                        const float* __restrict__ obe,
                        float* __restrict__ agg,
                        float* __restrict__ out_pts){
  __shared__ __align__(16) unsigned short tile[4][32 * 256];   // 16 KB per wave
  const int lane = threadIdx.x & 63;
  const int wave = threadIdx.x >> 6;
  const int g = lane >> 4, t = lane & 15;
  const int m0 = blockIdx.x * 128 + wave * 32;   // 32 | NP
  if (m0 >= NP) return;                          // per-wave LDS: no barrier needed
  const int slotA = m0 + t, slotB = m0 + 16 + t;
  const int2 pA = pv[slotA];
  const int2 pB = pv[slotB];
  const int origA = pA.x, origB = pB.x;
  const int myv = pv[m0 + (lane & 31)].y;        // wave's 32 voxel ids

  // sequential fragment loads from sorted x0
  s16x8 bfA[4], bfB[4];
#pragma unroll
  for (int kc = 0; kc < 4; ++kc){
    bfA[kc] = *(const s16x8*)(x0 + (size_t)slotA * 128 + (kc * 4 + g) * 8);
    bfB[kc] = *(const s16x8*)(x0 + (size_t)slotB * 128 + (kc * 4 + g) * 8);
  }

  f32x4 d1a[8], d1b[8];
  gemm2x<4, 8>(bfA, bfB, w1p, lane, d1a, d1b);
  bias_ln_relu_sw<8, 128>(d1a, d1b, b1, g1, be1, g);
  s16x8 f2a[4], f2b[4];
  to_frags<8>(d1a, f2a); to_frags<8>(d1b, f2b);

  f32x4 d2a[16], d2b[16];
  gemm2x<4, 16>(f2a, f2b, w2p, lane, d2a, d2b);
  bias_ln_relu_sw<16, 256>(d2a, d2b, b2, g2, be2, g);
  s16x8 f3a[8], f3b[8];
  to_frags<16>(d2a, f3a); to_frags<16>(d2b, f3b);

  // stage y2 tile to this wave's LDS quarter (swizzled 16B slots)
  unsigned short* my = tile[wave];
  const int rA = t, rB = t + 16;
#pragma unroll
  for (int kc = 0; kc < 8; ++kc){
    int s = kc * 4 + g;
    int spA = (s & ~7) | ((s & 7) ^ (rA & 7));
    int spB = (s & ~7) | ((s & 7) ^ (rB & 7));
    *(s16x8*)&my[rA * 256 + spA * 8] = f3a[kc];
    *(s16x8*)&my[rB * 256 + spB * 8] = f3b[kc];
  }

  // out layer (overlaps LDS write drain) -> scatter to original point order
  {
    f32x4 d3a[4], d3b[4];
    gemm2x<8, 4>(f3a, f3b, owp, lane, d3a, d3b);
    bias_ln_relu_sw<4, 64>(d3a, d3b, ob, og, obe, g);
#pragma unroll
    for (int n = 0; n < 4; ++n){
      *(f32x4*)(out_pts + (size_t)origA * 64 + n * 16 + g * 4) = d3a[n];
      *(f32x4*)(out_pts + (size_t)origB * 64 + n * 16 + g * 4) = d3b[n];
    }
  }

  // ---- chunked wave-uniform run walk (4 chunks x 8 rows; 8 ds_reads in flight) ----
  const int vleft  = (m0 > 0) ? pv[m0 - 1].y : -1;
  const int vright = (m0 + 32 < NP) ? pv[m0 + 32].y : -1;
  const int slot = lane >> 1;                 // 16B slot holding lane's channels
  const int half = (lane & 1) * 4;            // u16 offset within slot
  unsigned int q0 = 0, q1 = 0;
  int cur = __shfl(myv, 0);
  int rs = 0;
#pragma unroll
  for (int rc = 0; rc < 4; ++rc){
    u32x2 dreg[8];
#pragma unroll
    for (int rr = 0; rr < 8; ++rr){
      int r = rc * 8 + rr;
      int sp = (slot & ~7) | ((slot & 7) ^ (r & 7));
      dreg[rr] = *(const u32x2*)&my[r * 256 + sp * 8 + half];
    }
#pragma unroll
    for (int rr = 0; rr < 8; ++rr){
      int r = rc * 8 + rr;
      int v = __shfl(myv, r);                 // uniform broadcast (readlane)
      if (v != cur){
        flush4(agg, cur, lane, q0, q1, rs == 0 && cur == vleft);
        q0 = 0; q1 = 0; cur = v; rs = r;
      }
      q0 = pkmaxu16(q0, dreg[rr][0]);
      q1 = pkmaxu16(q1, dreg[rr][1]);
    }
  }
  flush4(agg, cur, lane, q0, q1, (rs == 0 && cur == vleft) || cur == vright);
}

// ---------------- fused voxel pipeline (agg f32 -> pl1 -> pl2, pipelined weights) ----------------
__global__ __launch_bounds__(256, 2)
void vox_fused_kernel(const float* __restrict__ agg,
                      const unsigned short* __restrict__ pw1p,
                      const unsigned short* __restrict__ pw2p,
                      const float* __restrict__ pb1, const float* __restrict__ pg1,
                      const float* __restrict__ pbe1,
                      const float* __restrict__ pb2, const float* __restrict__ pg2,
                      const float* __restrict__ pbe2,
                      float* __restrict__ out_vox){
  const int lane = threadIdx.x & 63;
  const int wave = threadIdx.x >> 6;
  const int m0 = blockIdx.x * 128 + wave * 32;
  if (m0 >= NV) return;
  const int g = lane >> 4, t = lane & 15;
  const size_t mA = m0 + t, mB = m0 + 16 + t;

  s16x8 bfA[8], bfB[8];
#pragma unroll
  for (int kc = 0; kc < 8; ++kc){
    const float* pa = agg + mA * 256 + kc * 32 + g * 8;
    const float* pb = agg + mB * 256 + kc * 32 + g * 8;
    f32x4 a0 = *(const f32x4*)pa, a1 = *(const f32x4*)(pa + 4);
    f32x4 b0 = *(const f32x4*)pb, b1v = *(const f32x4*)(pb + 4);
    u32x4 ta, tb;
    ta[0] = cvtpk(a0[0], a0[1]); ta[1] = cvtpk(a0[2], a0[3]);
    ta[2] = cvtpk(a1[0], a1[1]); ta[3] = cvtpk(a1[2], a1[3]);
    tb[0] = cvtpk(b0[0], b0[1]); tb[1] = cvtpk(b0[2], b0[3]);
    tb[2] = cvtpk(b1v[0], b1v[1]); tb[3] = cvtpk(b1v[2], b1v[3]);
    bfA[kc] = __builtin_bit_cast(s16x8, ta);
    bfB[kc] = __builtin_bit_cast(s16x8, tb);
  }
  f32x4 da[16], db[16];
  gemm2x_pl<8, 16>(bfA, bfB, pw1p, lane, da, db);
  bias_ln_relu_sw<16, 256>(da, db, pb1, pg1, pbe1, g);

  s16x8 fa[8], fb[8];
  to_frags<16>(da, fa); to_frags<16>(db, fb);

  gemm2x_pl<8, 16>(fa, fb, pw2p, lane, da, db);
  bias_ln_relu_sw<16, 256>(da, db, pb2, pg2, pbe2, g);
#pragma unroll
  for (int n = 0; n < 16; ++n){
    *(f32x4*)(out_vox + mA * 256 + n * 16 + g * 4) = da[n];
    *(f32x4*)(out_vox + mB * 256 + n * 16 + g * 4) = db[n];
  }
}

extern "C" void kernel_launch(void* const* d_in, const int* in_sizes, int n_in,
                              void* d_out, int out_size, void* d_ws, size_t ws_size,
                              hipStream_t stream){
  const float* features  = (const float*)d_in[1];
  const int*   coors     = (const int*)  d_in[2];
  const float* f_cluster = (const float*)d_in[3];
  const float* w1  = (const float*)d_in[4];
  const float* b1  = (const float*)d_in[5];
  const float* g1  = (const float*)d_in[6];
  const float* be1 = (const float*)d_in[7];
  const float* w2  = (const float*)d_in[8];
  const float* b2  = (const float*)d_in[9];
  const float* g2  = (const float*)d_in[10];
  const float* be2 = (const float*)d_in[11];
  const float* pw1 = (const float*)d_in[12];
  const float* pb1 = (const float*)d_in[13];
  const float* pg1 = (const float*)d_in[14];
  const float* pbe1= (const float*)d_in[15];
  const float* pw2 = (const float*)d_in[16];
  const float* pb2 = (const float*)d_in[17];
  const float* pg2 = (const float*)d_in[18];
  const float* pbe2= (const float*)d_in[19];
  const float* ow  = (const float*)d_in[20];
  const float* ob  = (const float*)d_in[21];
  const float* og  = (const float*)d_in[22];
  const float* obe = (const float*)d_in[23];

  char* ws = (char*)d_ws;
  float* aggf   = (float*)(ws + 0);                          // 61,440,000 B
  int* counts   = (int*)(ws + 61440000ull);                  // memset with aggf
  int* cursor   = (int*)(ws + 61800000ull);
  int2* pv      = (int2*)(ws + 62100000ull);                 // 4,000,000 B
  unsigned int* x0u = (unsigned int*)(ws + 66200000ull);     // 128,000,000 B (sorted order)
  unsigned short* x0 = (unsigned short*)x0u;
  unsigned short* w1p = (unsigned short*)(ws + 195000000ull);
  unsigned short* w2p = (unsigned short*)(ws + 195000000ull + 1*262144ull);
  unsigned short* owp = (unsigned short*)(ws + 195000000ull + 2*262144ull);
  unsigned short* pw1p= (unsigned short*)(ws + 195000000ull + 3*262144ull);
  unsigned short* pw2p= (unsigned short*)(ws + 195000000ull + 4*262144ull);

  float* outp      = (float*)d_out;
  float* out_pts   = outp;                       // [N,64]
  float* out_vox   = outp + 32000000;            // [V,256]
  float* out_coors = outp + 47360000;            // [V] as float

  hipMemsetAsync(ws, 0, 61440000ull + (size_t)NV * sizeof(int), stream);

  pack_hist_kernel<<<2048, 256, 0, stream>>>(w1, w2, ow, pw1, pw2,
                                             w1p, w2p, owp, pw1p, pw2p,
                                             out_coors, coors, counts);

  scan_kernel<<<1, 1024, 0, stream>>>(counts, cursor);

  scatter_prep2_kernel<<<2048, 256, 0, stream>>>(coors, cursor, features, f_cluster,
                                                 pv, x0u);

  point_fused_kernel<<<(NP + 127) / 128, 256, 0, stream>>>(
      x0, pv, w1p, w2p, owp,
      b1, g1, be1, b2, g2, be2, ob, og, obe, aggf, out_pts);

  vox_fused_kernel<<<(NV + 127) / 128, 256, 0, stream>>>(
      aggf, pw1p, pw2p, pb1, pg1, pbe1, pb2, pg2, pbe2, out_vox);
}